// Round 1
// baseline (70.772 us; speedup 1.0000x reference)
//
#include <hip/hip_runtime.h>
#include <math.h>

#define BB_ 512
#define NN_ 128
#define DD_ 64
#define NE_ 6
#define NB_ 4

// workspace layout (floats)
#define WS_PAIRE 0                 // 144 floats: pairE[k][ti][tj]
#define WS_AE    144               // 6
#define WS_ENT   152               // 6
#define WS_TS    160               // 128*6*256 stability layer1 table
#define WS_TD    (160 + 128*6*256) // 128*6*256 druglikeness layer1 table

// ---------------------------------------------------------------------------
// Kernel A: tiny tables. blocks 0..143 -> pairE entry; 144 -> ae; 145 -> ent
// ---------------------------------------------------------------------------
__global__ __launch_bounds__(64) void k_tables(
    const float* __restrict__ emb, const float* __restrict__ ae_w,
    const float* __restrict__ ae_b, const float* __restrict__ ent_w,
    const float* __restrict__ ent_b, const float* __restrict__ bW,
    float* __restrict__ ws) {
  int blk = blockIdx.x;
  int lane = threadIdx.x;  // 0..63
  if (blk < 144) {
    int k = blk / 36;
    int rem = blk - k * 36;
    int ti = rem / 6, tj = rem - (rem / 6) * 6;
    int d = lane;
    const float* Wrow = bW + ((size_t)k * DD_ + d) * DD_;
    float acc = 0.f;
#pragma unroll 8
    for (int e = 0; e < DD_; ++e) acc += Wrow[e] * emb[tj * DD_ + e];
    float c = emb[ti * DD_ + d] * acc;
#pragma unroll
    for (int off = 32; off > 0; off >>= 1) c += __shfl_down(c, off);
    if (lane == 0) ws[WS_PAIRE + blk] = c;
  } else {
    const float* wv = (blk == 144) ? ae_w : ent_w;
    const float* bv = (blk == 144) ? ae_b : ent_b;
    int dst = (blk == 144) ? WS_AE : WS_ENT;
    for (int t = 0; t < NE_; ++t) {
      float c = emb[t * DD_ + lane] * wv[lane];
#pragma unroll
      for (int off = 32; off > 0; off >>= 1) c += __shfl_down(c, off);
      if (lane == 0) ws[dst + t] = c + bv[0];
    }
  }
}

// ---------------------------------------------------------------------------
// Kernel B: layer-1 tables. T[n][t][o] = sum_d emb[t][d] * W1[n*64+d][o]
// grid 256: blockIdx = n*2 + which ; 256 threads = o
// ---------------------------------------------------------------------------
__global__ __launch_bounds__(256) void k_mlp1(
    const float* __restrict__ emb, const float* __restrict__ sW1,
    const float* __restrict__ dW1, float* __restrict__ ws) {
  int n = blockIdx.x >> 1;
  int which = blockIdx.x & 1;
  const float* W1 = which ? dW1 : sW1;
  float* T = ws + (which ? WS_TD : WS_TS);
  __shared__ float e_s[NE_ * DD_];
  int tid = threadIdx.x;
  for (int i = tid; i < NE_ * DD_; i += 256) e_s[i] = emb[i];
  __syncthreads();
  int o = tid;
  float acc[NE_] = {0.f, 0.f, 0.f, 0.f, 0.f, 0.f};
  const float* Wp = W1 + (size_t)(n * DD_) * 256 + o;
#pragma unroll 8
  for (int d = 0; d < DD_; ++d) {
    float w = Wp[(size_t)d * 256];
#pragma unroll
    for (int t = 0; t < NE_; ++t) acc[t] += e_s[t * DD_ + d] * w;
  }
#pragma unroll
  for (int t = 0; t < NE_; ++t) T[(n * NE_ + t) * 256 + o] = acc[t];
}

// ---------------------------------------------------------------------------
// Kernel C: per-molecule fused kernel. grid 512 (one block per batch), 256 thr
// ---------------------------------------------------------------------------
__device__ __forceinline__ float block_reduce256(float v, volatile float* red4,
                                                 int tid) {
#pragma unroll
  for (int off = 32; off > 0; off >>= 1) v += __shfl_down(v, off);
  __syncthreads();
  if ((tid & 63) == 0) red4[tid >> 6] = v;
  __syncthreads();
  return red4[0] + red4[1] + red4[2] + red4[3];
}

__global__ __launch_bounds__(256) void k_main(
    const int* __restrict__ atom_types, const float* __restrict__ pos,
    const int* __restrict__ bonds, const float* __restrict__ emb,
    const float* __restrict__ bb, const float* __restrict__ sb1,
    const float* __restrict__ sW2, const float* __restrict__ sb2,
    const float* __restrict__ sW3, const float* __restrict__ sb3,
    const float* __restrict__ db1, const float* __restrict__ dW2,
    const float* __restrict__ db2, const float* __restrict__ dW3,
    const float* __restrict__ db3, const float* __restrict__ ws,
    float* __restrict__ out) {
  int b = blockIdx.x;
  int tid = threadIdx.x;

  __shared__ float e_s[NE_ * DD_];
  __shared__ float pairE[144];
  __shared__ float aev[NE_], entv[NE_], bbv[NB_];
  __shared__ int types[NN_];
  __shared__ float px[NN_], py[NN_], pz[NN_];
  __shared__ float red4[4];
  __shared__ float sc[8];
  __shared__ float h1s[256], h1d[256];
  __shared__ float h2s[128], h2d[128];
  __shared__ float red[256];

  for (int i = tid; i < NE_ * DD_; i += 256) e_s[i] = emb[i];
  for (int i = tid; i < 144; i += 256) pairE[i] = ws[WS_PAIRE + i];
  if (tid < NE_) {
    aev[tid] = ws[WS_AE + tid];
    entv[tid] = ws[WS_ENT + tid];
  }
  if (tid < NB_) bbv[tid] = bb[tid];
  if (tid < NN_) types[tid] = atom_types[b * NN_ + tid];
  for (int i = tid; i < NN_ * 3; i += 256) {
    float v = pos[(size_t)b * NN_ * 3 + i];
    int n = i / 3, c = i - n * 3;
    if (c == 0) px[n] = v;
    else if (c == 1) py[n] = v;
    else pz[n] = v;
  }
  __syncthreads();

  // ---- write x output: out[2048 + b*8192 + n*64 + d] = emb[types[n]][d]
  {
    float4* out4 = (float4*)(out + 2048 + (size_t)b * (NN_ * DD_));
#pragma unroll
    for (int li = tid; li < (NN_ * DD_) / 4; li += 256) {
      int n = li >> 4;
      int d0 = (li & 15) << 2;
      out4[li] = *(const float4*)&e_s[types[n] * DD_ + d0];
    }
  }

  // ---- per-thread partials
  float ae_p = 0.f, ent_p = 0.f;
  if (tid < NN_) {
    int t = types[tid];
    ae_p = aev[t];
    ent_p = entv[t];
  }

  // ---- bonds: int4 sweep of full [128][128] matrix, use j>i entries
  float bond_p = 0.f;
  {
    const int4* b4 = (const int4*)(bonds + (size_t)b * NN_ * NN_);
#pragma unroll 4
    for (int li = tid; li < (NN_ * NN_) / 4; li += 256) {
      int4 v = b4[li];
      int i = li >> 5;
      int j0 = (li & 31) << 2;
      int ti6 = types[i] * 6;
      if (j0 + 0 > i && v.x > 0)
        bond_p += pairE[(v.x - 1) * 36 + ti6 + types[j0 + 0]] + bbv[v.x - 1];
      if (j0 + 1 > i && v.y > 0)
        bond_p += pairE[(v.y - 1) * 36 + ti6 + types[j0 + 1]] + bbv[v.y - 1];
      if (j0 + 2 > i && v.z > 0)
        bond_p += pairE[(v.z - 1) * 36 + ti6 + types[j0 + 2]] + bbv[v.z - 1];
      if (j0 + 3 > i && v.w > 0)
        bond_p += pairE[(v.w - 1) * 36 + ti6 + types[j0 + 3]] + bbv[v.w - 1];
    }
  }

  // ---- vdW over i<j pairs
  float vdw_p = 0.f;
  {
#pragma unroll 2
    for (int li = tid; li < NN_ * NN_; li += 256) {
      int i = li >> 7;
      int j = li & 127;
      if (j > i) {
        float dx = px[i] - px[j];
        float dy = py[i] - py[j];
        float dz = pz[i] - pz[j];
        float d2 = dx * dx + dy * dy + dz * dz;
        if (d2 > 0.f) {
          float inv2 = 1.f / d2;
          float inv6 = inv2 * inv2 * inv2;
          vdw_p += 0.4f * (inv6 * inv6 - inv6);
        }
      }
    }
  }

  // ---- position variance (ddof=1)
  float vx = (tid < NN_) ? px[tid] : 0.f;
  float vy = (tid < NN_) ? py[tid] : 0.f;
  float vz = (tid < NN_) ? pz[tid] : 0.f;
  float sx = block_reduce256(vx, red4, tid);
  float sy = block_reduce256(vy, red4, tid);
  float sz = block_reduce256(vz, red4, tid);
  float mx = sx * (1.f / NN_), my = sy * (1.f / NN_), mz = sz * (1.f / NN_);
  float dev = 0.f;
  if (tid < NN_) {
    float a = px[tid] - mx, c = py[tid] - my, e = pz[tid] - mz;
    dev = a * a + c * c + e * e;
  }
  float devsum = block_reduce256(dev, red4, tid);
  float pos_var = devsum * (1.f / (NN_ - 1));

  // ---- energy / entropy reductions
  float e_total = block_reduce256(ae_p + bond_p + vdw_p, red4, tid);
  float s_total = block_reduce256(ent_p, red4, tid);

  // ---- MLP layer 1 via tables (L2-resident)
  {
    int o = tid;
    float accs = sb1[o];
    float accd = db1[o];
    const float* Ts = ws + WS_TS + o;
    const float* Td = ws + WS_TD + o;
#pragma unroll 4
    for (int n = 0; n < NN_; ++n) {
      int t = types[n];
      accs += Ts[(size_t)(n * NE_ + t) * 256];
      accd += Td[(size_t)(n * NE_ + t) * 256];
    }
    h1s[o] = fmaxf(accs, 0.f);
    h1d[o] = fmaxf(accd, 0.f);
  }
  __syncthreads();

  // ---- MLP layer 2
  {
    float acc2;
    if (tid < 128) {
      int k = tid;
      acc2 = sb2[k];
#pragma unroll 4
      for (int o = 0; o < 256; ++o) acc2 += h1s[o] * sW2[(size_t)o * 128 + k];
      h2s[k] = fmaxf(acc2, 0.f);
    } else {
      int k = tid - 128;
      acc2 = db2[k];
#pragma unroll 4
      for (int o = 0; o < 256; ++o) acc2 += h1d[o] * dW2[(size_t)o * 128 + k];
      h2d[k] = fmaxf(acc2, 0.f);
    }
  }
  __syncthreads();

  // ---- MLP layer 3 + sigmoid
  red[tid] = (tid < 128) ? h2s[tid] * sW3[tid] : h2d[tid - 128] * dW3[tid - 128];
  __syncthreads();
#pragma unroll
  for (int s = 64; s > 0; s >>= 1) {
    if ((tid & 127) < s) red[tid] += red[tid + s];
    __syncthreads();
  }
  if (tid == 0) {
    float stab_pre = red[0] + sb3[0];
    float drug_pre = red[128] + db3[0];
    out[b] = e_total;
    out[BB_ + b] = s_total + logf(1.f + pos_var);
    out[2 * BB_ + b] = 1.f / (1.f + expf(-stab_pre));
    out[3 * BB_ + b] = 1.f / (1.f + expf(-drug_pre));
  }
}

// ---------------------------------------------------------------------------
extern "C" void kernel_launch(void* const* d_in, const int* in_sizes, int n_in,
                              void* d_out, int out_size, void* d_ws,
                              size_t ws_size, hipStream_t stream) {
  const int* atom_types = (const int*)d_in[0];
  const float* positions = (const float*)d_in[1];
  const int* bonds = (const int*)d_in[2];
  const float* emb = (const float*)d_in[3];
  const float* ae_w = (const float*)d_in[4];
  const float* ae_b = (const float*)d_in[5];
  const float* ent_w = (const float*)d_in[6];
  const float* ent_b = (const float*)d_in[7];
  const float* bW = (const float*)d_in[8];
  const float* bb = (const float*)d_in[9];
  const float* sW1 = (const float*)d_in[10];
  const float* sb1 = (const float*)d_in[11];
  const float* sW2 = (const float*)d_in[12];
  const float* sb2 = (const float*)d_in[13];
  const float* sW3 = (const float*)d_in[14];
  const float* sb3 = (const float*)d_in[15];
  const float* dW1 = (const float*)d_in[16];
  const float* db1 = (const float*)d_in[17];
  const float* dW2 = (const float*)d_in[18];
  const float* db2 = (const float*)d_in[19];
  const float* dW3 = (const float*)d_in[20];
  const float* db3 = (const float*)d_in[21];
  float* out = (float*)d_out;
  float* ws = (float*)d_ws;

  hipLaunchKernelGGL(k_tables, dim3(146), dim3(64), 0, stream, emb, ae_w, ae_b,
                     ent_w, ent_b, bW, ws);
  hipLaunchKernelGGL(k_mlp1, dim3(256), dim3(256), 0, stream, emb, sW1, dW1,
                     ws);
  hipLaunchKernelGGL(k_main, dim3(512), dim3(256), 0, stream, atom_types,
                     positions, bonds, emb, bb, sb1, sW2, sb2, sW3, sb3, db1,
                     dW2, db2, dW3, db3, ws, out);
}

// Round 2
// 49.650 us; speedup vs baseline: 1.4254x; 1.4254x over previous
//
#include <hip/hip_runtime.h>
#include <math.h>

#define BB_ 512
#define NN_ 128
#define DD_ 64
#define NE_ 6
#define NB_ 4

// workspace layout (floats)
#define WS_PAIRE 0                 // 144 floats: pairE[k][ti][tj]
#define WS_AE    144               // 6
#define WS_ENT   152               // 6
#define WS_TS    160               // 128*6*256 stability layer1 table
#define WS_TD    (160 + 128*6*256) // 128*6*256 druglikeness layer1 table

// ---------------------------------------------------------------------------
// Kernel A: tiny tables. blocks 0..143 -> pairE entry; 144 -> ae; 145 -> ent
// ---------------------------------------------------------------------------
__global__ __launch_bounds__(64) void k_tables(
    const float* __restrict__ emb, const float* __restrict__ ae_w,
    const float* __restrict__ ae_b, const float* __restrict__ ent_w,
    const float* __restrict__ ent_b, const float* __restrict__ bW,
    float* __restrict__ ws) {
  int blk = blockIdx.x;
  int lane = threadIdx.x;  // 0..63
  if (blk < 144) {
    int k = blk / 36;
    int rem = blk - k * 36;
    int ti = rem / 6, tj = rem - (rem / 6) * 6;
    int d = lane;
    const float* Wrow = bW + ((size_t)k * DD_ + d) * DD_;
    float acc = 0.f;
#pragma unroll 8
    for (int e = 0; e < DD_; ++e) acc += Wrow[e] * emb[tj * DD_ + e];
    float c = emb[ti * DD_ + d] * acc;
#pragma unroll
    for (int off = 32; off > 0; off >>= 1) c += __shfl_down(c, off);
    if (lane == 0) ws[WS_PAIRE + blk] = c;
  } else {
    const float* wv = (blk == 144) ? ae_w : ent_w;
    const float* bv = (blk == 144) ? ae_b : ent_b;
    int dst = (blk == 144) ? WS_AE : WS_ENT;
    for (int t = 0; t < NE_; ++t) {
      float c = emb[t * DD_ + lane] * wv[lane];
#pragma unroll
      for (int off = 32; off > 0; off >>= 1) c += __shfl_down(c, off);
      if (lane == 0) ws[dst + t] = c + bv[0];
    }
  }
}

// ---------------------------------------------------------------------------
// Kernel B: layer-1 tables. T[n][t][o] = sum_d emb[t][d] * W1[n*64+d][o]
// grid 256: blockIdx = n*2 + which ; 256 threads = o
// ---------------------------------------------------------------------------
__global__ __launch_bounds__(256) void k_mlp1(
    const float* __restrict__ emb, const float* __restrict__ sW1,
    const float* __restrict__ dW1, float* __restrict__ ws) {
  int n = blockIdx.x >> 1;
  int which = blockIdx.x & 1;
  const float* W1 = which ? dW1 : sW1;
  float* T = ws + (which ? WS_TD : WS_TS);
  __shared__ float e_s[NE_ * DD_];
  int tid = threadIdx.x;
  for (int i = tid; i < NE_ * DD_; i += 256) e_s[i] = emb[i];
  __syncthreads();
  int o = tid;
  float acc[NE_] = {0.f, 0.f, 0.f, 0.f, 0.f, 0.f};
  const float* Wp = W1 + (size_t)(n * DD_) * 256 + o;
#pragma unroll 8
  for (int d = 0; d < DD_; ++d) {
    float w = Wp[(size_t)d * 256];
#pragma unroll
    for (int t = 0; t < NE_; ++t) acc[t] += e_s[t * DD_ + d] * w;
  }
#pragma unroll
  for (int t = 0; t < NE_; ++t) T[(n * NE_ + t) * 256 + o] = acc[t];
}

// ---------------------------------------------------------------------------
// block reduce over 256 threads (4 waves)
// ---------------------------------------------------------------------------
__device__ __forceinline__ float block_reduce256(float v, volatile float* red4,
                                                 int tid) {
#pragma unroll
  for (int off = 32; off > 0; off >>= 1) v += __shfl_down(v, off);
  __syncthreads();
  if ((tid & 63) == 0) red4[tid >> 6] = v;
  __syncthreads();
  return red4[0] + red4[1] + red4[2] + red4[3];
}

// ---------------------------------------------------------------------------
// Kernel C: fused per-molecule kernel. grid (512, 6), 256 threads.
//   role 0..3: quarter of bonds+vdW rows (+role0: variance & entropy log term)
//              -> atomicAdd into out[b], out[512+b] (zeroed by memset)
//   role 4: stability MLP + x[n<64] write ; role 5: druglikeness MLP + x[n>=64]
// ---------------------------------------------------------------------------
__global__ __launch_bounds__(256) void k_fused(
    const int* __restrict__ atom_types, const float* __restrict__ pos,
    const int* __restrict__ bonds, const float* __restrict__ emb,
    const float* __restrict__ bb, const float* __restrict__ sb1,
    const float* __restrict__ sW2, const float* __restrict__ sb2,
    const float* __restrict__ sW3, const float* __restrict__ sb3,
    const float* __restrict__ db1, const float* __restrict__ dW2,
    const float* __restrict__ db2, const float* __restrict__ dW3,
    const float* __restrict__ db3, const float* __restrict__ ws,
    float* __restrict__ out) {
  int b = blockIdx.x;
  int role = blockIdx.y;
  int tid = threadIdx.x;

  __shared__ int types[NN_];
  __shared__ float red4[4];

  if (tid < NN_) types[tid] = atom_types[b * NN_ + tid];

  if (role < 4) {
    // ================= energy quarter =================
    __shared__ float px[NN_], py[NN_], pz[NN_];
    __shared__ float pairE[144];
    __shared__ float aev[NE_], entv[NE_], bbv[NB_];
    for (int i = tid; i < 144; i += 256) pairE[i] = ws[WS_PAIRE + i];
    if (tid < NE_) {
      aev[tid] = ws[WS_AE + tid];
      entv[tid] = ws[WS_ENT + tid];
    }
    if (tid < NB_) bbv[tid] = bb[tid];
    for (int i = tid; i < NN_ * 3; i += 256) {
      float v = pos[(size_t)b * NN_ * 3 + i];
      int n = i / 3, c = i - n * 3;
      if (c == 0) px[n] = v;
      else if (c == 1) py[n] = v;
      else pz[n] = v;
    }
    __syncthreads();

    int q = role;
    float ae_p = 0.f, ent_p = 0.f;
    if (tid < 32) {
      int t = types[q * 32 + tid];
      ae_p = aev[t];
      ent_p = entv[t];
    }

    // bonds rows [q*32, q*32+32): 32*32 int4 = 1024 / 256 thr = 4 iters
    float bond_p = 0.f;
    {
      const int4* b4 =
          (const int4*)(bonds + (size_t)b * NN_ * NN_ + (size_t)q * 32 * NN_);
#pragma unroll 4
      for (int li = tid; li < 1024; li += 256) {
        int4 v = b4[li];
        int i = q * 32 + (li >> 5);
        int j0 = (li & 31) << 2;
        int ti6 = types[i] * 6;
        if (j0 + 0 > i && v.x > 0)
          bond_p += pairE[(v.x - 1) * 36 + ti6 + types[j0 + 0]] + bbv[v.x - 1];
        if (j0 + 1 > i && v.y > 0)
          bond_p += pairE[(v.y - 1) * 36 + ti6 + types[j0 + 1]] + bbv[v.y - 1];
        if (j0 + 2 > i && v.z > 0)
          bond_p += pairE[(v.z - 1) * 36 + ti6 + types[j0 + 2]] + bbv[v.z - 1];
        if (j0 + 3 > i && v.w > 0)
          bond_p += pairE[(v.w - 1) * 36 + ti6 + types[j0 + 3]] + bbv[v.w - 1];
      }
    }

    // vdW rows [q*32, q*32+32): 32*128 / 256 = 16 iters
    float vdw_p = 0.f;
#pragma unroll 4
    for (int li = tid; li < 32 * NN_; li += 256) {
      int i = q * 32 + (li >> 7);
      int j = li & 127;
      if (j > i) {
        float dx = px[i] - px[j];
        float dy = py[i] - py[j];
        float dz = pz[i] - pz[j];
        float d2 = dx * dx + dy * dy + dz * dz;
        if (d2 > 0.f) {
          float inv2 = 1.f / d2;
          float inv6 = inv2 * inv2 * inv2;
          vdw_p += 0.4f * (inv6 * inv6 - inv6);
        }
      }
    }

    // variance & log term only in role 0
    float extra = 0.f;
    if (q == 0) {
      float vx = (tid < NN_) ? px[tid] : 0.f;
      float vy = (tid < NN_) ? py[tid] : 0.f;
      float vz = (tid < NN_) ? pz[tid] : 0.f;
      float sx = block_reduce256(vx, red4, tid);
      float sy = block_reduce256(vy, red4, tid);
      float sz = block_reduce256(vz, red4, tid);
      float mx = sx * (1.f / NN_), my = sy * (1.f / NN_), mz = sz * (1.f / NN_);
      float dev = 0.f;
      if (tid < NN_) {
        float a = px[tid] - mx, c = py[tid] - my, e = pz[tid] - mz;
        dev = a * a + c * c + e * e;
      }
      float devsum = block_reduce256(dev, red4, tid);
      if (tid == 0) extra = logf(1.f + devsum * (1.f / (NN_ - 1)));
    }

    float esum = block_reduce256(ae_p + bond_p + vdw_p, red4, tid);
    float ssum = block_reduce256(ent_p, red4, tid);
    if (tid == 0) {
      atomicAdd(&out[b], esum);
      atomicAdd(&out[BB_ + b], ssum + extra);
    }
  } else {
    // ================= MLP head =================
    int which = role - 4;  // 0 stability, 1 druglikeness
    __shared__ float e_s[NE_ * DD_];
    __shared__ float h1[256];
    __shared__ float h2[128];
    __shared__ float red[256];
    for (int i = tid; i < NE_ * DD_; i += 256) e_s[i] = emb[i];
    __syncthreads();

    // x write: role4 -> n in [0,64), role5 -> n in [64,128)
    {
      float4* out4 = (float4*)(out + 2048 + (size_t)b * (NN_ * DD_) +
                               (size_t)which * 64 * DD_);
#pragma unroll 4
      for (int li = tid; li < 64 * DD_ / 4; li += 256) {
        int n = which * 64 + (li >> 4);
        int d0 = (li & 15) << 2;
        out4[li] = *(const float4*)&e_s[types[n] * DD_ + d0];
      }
    }

    // layer 1 via table gather (coalesced rows, L2-resident)
    {
      const float* T = ws + (which ? WS_TD : WS_TS) + tid;
      const float* b1 = which ? db1 : sb1;
      float acc = b1[tid];
#pragma unroll 8
      for (int n = 0; n < NN_; ++n)
        acc += T[(size_t)(n * NE_ + types[n]) * 256];
      h1[tid] = fmaxf(acc, 0.f);
    }
    __syncthreads();

    // layer 2, split-K over 2 halves
    {
      const float* W2 = which ? dW2 : sW2;
      int k = tid & 127, h = tid >> 7;
      const float* W2p = W2 + (size_t)(h * 128) * 128 + k;
      const float* h1p = h1 + h * 128;
      float acc2 = 0.f;
#pragma unroll 8
      for (int o = 0; o < 128; ++o) acc2 += h1p[o] * W2p[(size_t)o * 128];
      red[tid] = acc2;
    }
    __syncthreads();
    {
      const float* b2 = which ? db2 : sb2;
      if (tid < 128) h2[tid] = fmaxf(b2[tid] + red[tid] + red[tid + 128], 0.f);
    }
    __syncthreads();

    // layer 3 + sigmoid
    {
      const float* W3 = which ? dW3 : sW3;
      float p = (tid < 128) ? h2[tid] * W3[tid] : 0.f;
      float s = block_reduce256(p, red4, tid);
      if (tid == 0) {
        const float* b3 = which ? db3 : sb3;
        out[(2 + which) * BB_ + b] = 1.f / (1.f + expf(-(s + b3[0])));
      }
    }
  }
}

// ---------------------------------------------------------------------------
extern "C" void kernel_launch(void* const* d_in, const int* in_sizes, int n_in,
                              void* d_out, int out_size, void* d_ws,
                              size_t ws_size, hipStream_t stream) {
  const int* atom_types = (const int*)d_in[0];
  const float* positions = (const float*)d_in[1];
  const int* bonds = (const int*)d_in[2];
  const float* emb = (const float*)d_in[3];
  const float* ae_w = (const float*)d_in[4];
  const float* ae_b = (const float*)d_in[5];
  const float* ent_w = (const float*)d_in[6];
  const float* ent_b = (const float*)d_in[7];
  const float* bW = (const float*)d_in[8];
  const float* bb = (const float*)d_in[9];
  const float* sW1 = (const float*)d_in[10];
  const float* sb1 = (const float*)d_in[11];
  const float* sW2 = (const float*)d_in[12];
  const float* sb2 = (const float*)d_in[13];
  const float* sW3 = (const float*)d_in[14];
  const float* sb3 = (const float*)d_in[15];
  const float* dW1 = (const float*)d_in[16];
  const float* db1 = (const float*)d_in[17];
  const float* dW2 = (const float*)d_in[18];
  const float* db2 = (const float*)d_in[19];
  const float* dW3 = (const float*)d_in[20];
  const float* db3 = (const float*)d_in[21];
  float* out = (float*)d_out;
  float* ws = (float*)d_ws;

  // zero the atomic-accumulated region (energy + entropy)
  hipMemsetAsync(out, 0, 2 * BB_ * sizeof(float), stream);

  hipLaunchKernelGGL(k_tables, dim3(146), dim3(64), 0, stream, emb, ae_w, ae_b,
                     ent_w, ent_b, bW, ws);
  hipLaunchKernelGGL(k_mlp1, dim3(256), dim3(256), 0, stream, emb, sW1, dW1,
                     ws);
  hipLaunchKernelGGL(k_fused, dim3(512, 6), dim3(256), 0, stream, atom_types,
                     positions, bonds, emb, bb, sb1, sW2, sb2, sW3, sb3, db1,
                     dW2, db2, dW3, db3, ws, out);
}

// Round 3
// 36.778 us; speedup vs baseline: 1.9243x; 1.3500x over previous
//
#include <hip/hip_runtime.h>
#include <math.h>

#define BB_ 512
#define NN_ 128
#define DD_ 64
#define NE_ 6
#define NB_ 4

// workspace layout (floats)
#define WS_PAIRE 0                 // 144 floats: pairE[k][ti][tj]
#define WS_AE    144               // 6
#define WS_ENT   152               // 6
#define WS_TS    160               // 128*6*256 stability layer1 table
#define WS_TD    (160 + 128*6*256) // 128*6*256 druglikeness layer1 table

// ---------------------------------------------------------------------------
__device__ __forceinline__ float block_reduce256(float v, volatile float* red4,
                                                 int tid) {
#pragma unroll
  for (int off = 32; off > 0; off >>= 1) v += __shfl_down(v, off);
  __syncthreads();
  if ((tid & 63) == 0) red4[tid >> 6] = v;
  __syncthreads();
  return red4[0] + red4[1] + red4[2] + red4[3];
}

// ---------------------------------------------------------------------------
// k_pre: blocks 0..511  -> layer1 tables (n, which, ohalf)
//        block 512      -> zero out[0..1024)
//        blocks 513..656-> pairE entries (one per block)
//        block 657      -> ae/ent tables
// ---------------------------------------------------------------------------
__global__ __launch_bounds__(256, 4) void k_pre(
    const float* __restrict__ emb, const float* __restrict__ ae_w,
    const float* __restrict__ ae_b, const float* __restrict__ ent_w,
    const float* __restrict__ ent_b, const float* __restrict__ bW,
    const float* __restrict__ sW1, const float* __restrict__ dW1,
    float* __restrict__ ws, float* __restrict__ out) {
  int blk = blockIdx.x;
  int tid = threadIdx.x;

  if (blk < 512) {
    int n = blk >> 2;
    int which = (blk >> 1) & 1;
    int ohalf = blk & 1;
    const float* W1 = which ? dW1 : sW1;
    float* T = ws + (which ? WS_TD : WS_TS);
    __shared__ float e_s[NE_ * DD_];
    __shared__ float part[NE_][128];
    for (int i = tid; i < NE_ * DD_; i += 256) e_s[i] = emb[i];
    __syncthreads();
    int o_local = tid & 127;
    int dhalf = tid >> 7;
    int o = ohalf * 128 + o_local;
    float acc[NE_] = {0.f, 0.f, 0.f, 0.f, 0.f, 0.f};
    const float* Wp = W1 + ((size_t)(n * DD_ + dhalf * 32)) * 256 + o;
#pragma unroll 8
    for (int d = 0; d < 32; ++d) {
      float w = Wp[(size_t)d * 256];
#pragma unroll
      for (int t = 0; t < NE_; ++t) acc[t] += e_s[t * DD_ + dhalf * 32 + d] * w;
    }
    if (dhalf == 1) {
#pragma unroll
      for (int t = 0; t < NE_; ++t) part[t][o_local] = acc[t];
    }
    __syncthreads();
    if (dhalf == 0) {
#pragma unroll
      for (int t = 0; t < NE_; ++t)
        T[(n * NE_ + t) * 256 + o] = acc[t] + part[t][o_local];
    }
  } else if (blk == 512) {
    float4 z = make_float4(0.f, 0.f, 0.f, 0.f);
    ((float4*)out)[tid] = z;  // 256 float4 = 1024 floats (energy+entropy)
  } else if (blk < 657) {
    int e = blk - 513;
    int k = e / 36;
    int rem = e - k * 36;
    int ti = rem / 6, tj = rem - (rem / 6) * 6;
    int d = tid & 63;
    int qd = tid >> 6;
    const float* Wrow = bW + ((size_t)k * DD_ + d) * DD_ + qd * 16;
    const float* xj = emb + tj * DD_ + qd * 16;
    float a = 0.f;
#pragma unroll
    for (int u = 0; u < 16; ++u) a += Wrow[u] * xj[u];
    float c = emb[ti * DD_ + d] * a;
    __shared__ float red4[4];
    c = block_reduce256(c, red4, tid);
    if (tid == 0) ws[WS_PAIRE + e] = c;
  } else {
    int g = tid >> 6, lane = tid & 63;
    for (int idx = g; idx < 12; idx += 4) {
      int t = idx - (idx >= 6 ? 6 : 0);
      bool ent = idx >= 6;
      float c = emb[t * DD_ + lane] * (ent ? ent_w[lane] : ae_w[lane]);
#pragma unroll
      for (int off = 32; off > 0; off >>= 1) c += __shfl_down(c, off);
      if (lane == 0)
        ws[(ent ? WS_ENT : WS_AE) + t] = c + (ent ? ent_b[0] : ae_b[0]);
    }
  }
}

// ---------------------------------------------------------------------------
// k_fused: grid (512, 6), 256 threads.
//   role 0..3: quarter of bonds (triangle-skipped) + vdW rows
//              (+role0: variance & entropy log term) -> atomicAdd
//   role 4: stability MLP + x[n<64] write ; role 5: druglikeness + x[n>=64]
// ---------------------------------------------------------------------------
__global__ __launch_bounds__(256, 4) void k_fused(
    const int* __restrict__ atom_types, const float* __restrict__ pos,
    const int* __restrict__ bonds, const float* __restrict__ emb,
    const float* __restrict__ bb, const float* __restrict__ sb1,
    const float* __restrict__ sW2, const float* __restrict__ sb2,
    const float* __restrict__ sW3, const float* __restrict__ sb3,
    const float* __restrict__ db1, const float* __restrict__ dW2,
    const float* __restrict__ db2, const float* __restrict__ dW3,
    const float* __restrict__ db3, const float* __restrict__ ws,
    float* __restrict__ out) {
  int b = blockIdx.x;
  int role = blockIdx.y;
  int tid = threadIdx.x;

  __shared__ int types[NN_];
  __shared__ float red4[4];

  if (tid < NN_) types[tid] = atom_types[b * NN_ + tid];

  if (role < 4) {
    __shared__ float px[NN_], py[NN_], pz[NN_];
    __shared__ float pairE[144];
    __shared__ float aev[NE_], entv[NE_], bbv[NB_];
    for (int i = tid; i < 144; i += 256) pairE[i] = ws[WS_PAIRE + i];
    if (tid < NE_) {
      aev[tid] = ws[WS_AE + tid];
      entv[tid] = ws[WS_ENT + tid];
    }
    if (tid < NB_) bbv[tid] = bb[tid];
    for (int i = tid; i < NN_ * 3; i += 256) {
      float v = pos[(size_t)b * NN_ * 3 + i];
      int n = i / 3, c = i - n * 3;
      if (c == 0) px[n] = v;
      else if (c == 1) py[n] = v;
      else pz[n] = v;
    }
    __syncthreads();

    int q = role;
    float ae_p = 0.f, ent_p = 0.f;
    if (tid < 32) {
      int t = types[q * 32 + tid];
      ae_p = aev[t];
      ent_p = entv[t];
    }

    // bonds rows [q*32, q*32+32), triangle-skipped int4 loads
    float bond_p = 0.f;
    {
      const int4* b4 =
          (const int4*)(bonds + (size_t)b * NN_ * NN_ + (size_t)q * 32 * NN_);
#pragma unroll
      for (int it = 0; it < 4; ++it) {
        int li = tid + (it << 8);
        int ii = q * 32 + (li >> 5);
        int j0 = (li & 31) << 2;
        if (j0 + 3 > ii) {  // int4 intersects upper triangle
          int4 v = b4[li];
          int ti6 = types[ii] * 6;
          if (j0 + 0 > ii && v.x > 0)
            bond_p += pairE[(v.x - 1) * 36 + ti6 + types[j0 + 0]] + bbv[v.x - 1];
          if (j0 + 1 > ii && v.y > 0)
            bond_p += pairE[(v.y - 1) * 36 + ti6 + types[j0 + 1]] + bbv[v.y - 1];
          if (j0 + 2 > ii && v.z > 0)
            bond_p += pairE[(v.z - 1) * 36 + ti6 + types[j0 + 2]] + bbv[v.z - 1];
          if (j0 + 3 > ii && v.w > 0)
            bond_p += pairE[(v.w - 1) * 36 + ti6 + types[j0 + 3]] + bbv[v.w - 1];
        }
      }
    }

    // vdW rows: i fixed per thread, j = (tid&7) + 8*it
    float vdw_p = 0.f;
    {
      int i = q * 32 + (tid >> 3);
      float pix = px[i], piy = py[i], piz = pz[i];
      int jb = tid & 7;
#pragma unroll 4
      for (int it = 0; it < 16; ++it) {
        int j = jb + (it << 3);
        float dx = pix - px[j];
        float dy = piy - py[j];
        float dz = piz - pz[j];
        float d2 = dx * dx + dy * dy + dz * dz;
        if (j > i && d2 > 0.f) {
          float r = __builtin_amdgcn_rcpf(d2);
          float r6 = r * r * r;
          vdw_p += 0.4f * (r6 * r6 - r6);
        }
      }
    }

    float extra = 0.f;
    if (q == 0) {
      float vx = (tid < NN_) ? px[tid] : 0.f;
      float vy = (tid < NN_) ? py[tid] : 0.f;
      float vz = (tid < NN_) ? pz[tid] : 0.f;
      float sx = block_reduce256(vx, red4, tid);
      float sy = block_reduce256(vy, red4, tid);
      float sz = block_reduce256(vz, red4, tid);
      float mx = sx * (1.f / NN_), my = sy * (1.f / NN_), mz = sz * (1.f / NN_);
      float dev = 0.f;
      if (tid < NN_) {
        float a = px[tid] - mx, c = py[tid] - my, e = pz[tid] - mz;
        dev = a * a + c * c + e * e;
      }
      float devsum = block_reduce256(dev, red4, tid);
      if (tid == 0) extra = logf(1.f + devsum * (1.f / (NN_ - 1)));
    }

    float esum = block_reduce256(ae_p + bond_p + vdw_p, red4, tid);
    float ssum = block_reduce256(ent_p, red4, tid);
    if (tid == 0) {
      atomicAdd(&out[b], esum);
      atomicAdd(&out[BB_ + b], ssum + extra);
    }
  } else {
    int which = role - 4;
    __shared__ float e_s[NE_ * DD_];
    __shared__ float h1[256];
    __shared__ float h2[128];
    __shared__ float red[256];
    __shared__ int roff[NN_];
    for (int i = tid; i < NE_ * DD_; i += 256) e_s[i] = emb[i];
    if (tid < NN_) roff[tid] = (tid * NE_ + atom_types[b * NN_ + tid]) * 256;
    __syncthreads();

    // x write
    {
      float4* out4 = (float4*)(out + 2048 + (size_t)b * (NN_ * DD_) +
                               (size_t)which * 64 * DD_);
#pragma unroll 4
      for (int li = tid; li < 64 * DD_ / 4; li += 256) {
        int n = which * 64 + (li >> 4);
        int d0 = (li & 15) << 2;
        out4[li] = *(const float4*)&e_s[types[n] * DD_ + d0];
      }
    }

    // layer 1: 16-wide batched gather from L2-resident table
    {
      const float* Tb = ws + (which ? WS_TD : WS_TS) + tid;
      const float* b1 = which ? db1 : sb1;
      float acc = b1[tid];
#pragma unroll
      for (int n0 = 0; n0 < NN_; n0 += 16) {
        float v[16];
#pragma unroll
        for (int u = 0; u < 16; ++u) v[u] = Tb[roff[n0 + u]];
        float s = (((v[0] + v[1]) + (v[2] + v[3])) +
                   ((v[4] + v[5]) + (v[6] + v[7]))) +
                  (((v[8] + v[9]) + (v[10] + v[11])) +
                   ((v[12] + v[13]) + (v[14] + v[15])));
        acc += s;
      }
      h1[tid] = fmaxf(acc, 0.f);
    }
    __syncthreads();

    // layer 2: split-K over 2 halves, 8-wide batched
    {
      const float* W2 = which ? dW2 : sW2;
      int k = tid & 127, h = tid >> 7;
      const float* W2p = W2 + (size_t)(h * 128) * 128 + k;
      const float* h1p = h1 + h * 128;
      float acc2 = 0.f;
#pragma unroll
      for (int o0 = 0; o0 < 128; o0 += 8) {
        float w[8];
#pragma unroll
        for (int u = 0; u < 8; ++u) w[u] = W2p[(size_t)(o0 + u) * 128];
        float s = 0.f;
#pragma unroll
        for (int u = 0; u < 8; ++u) s += h1p[o0 + u] * w[u];
        acc2 += s;
      }
      red[tid] = acc2;
    }
    __syncthreads();
    {
      const float* b2 = which ? db2 : sb2;
      if (tid < 128) h2[tid] = fmaxf(b2[tid] + red[tid] + red[tid + 128], 0.f);
    }
    __syncthreads();

    {
      const float* W3 = which ? dW3 : sW3;
      float p = (tid < 128) ? h2[tid] * W3[tid] : 0.f;
      float s = block_reduce256(p, red4, tid);
      if (tid == 0) {
        const float* b3 = which ? db3 : sb3;
        out[(2 + which) * BB_ + b] = 1.f / (1.f + __expf(-(s + b3[0])));
      }
    }
  }
}

// ---------------------------------------------------------------------------
extern "C" void kernel_launch(void* const* d_in, const int* in_sizes, int n_in,
                              void* d_out, int out_size, void* d_ws,
                              size_t ws_size, hipStream_t stream) {
  const int* atom_types = (const int*)d_in[0];
  const float* positions = (const float*)d_in[1];
  const int* bonds = (const int*)d_in[2];
  const float* emb = (const float*)d_in[3];
  const float* ae_w = (const float*)d_in[4];
  const float* ae_b = (const float*)d_in[5];
  const float* ent_w = (const float*)d_in[6];
  const float* ent_b = (const float*)d_in[7];
  const float* bW = (const float*)d_in[8];
  const float* bb = (const float*)d_in[9];
  const float* sW1 = (const float*)d_in[10];
  const float* sb1 = (const float*)d_in[11];
  const float* sW2 = (const float*)d_in[12];
  const float* sb2 = (const float*)d_in[13];
  const float* sW3 = (const float*)d_in[14];
  const float* sb3 = (const float*)d_in[15];
  const float* dW1 = (const float*)d_in[16];
  const float* db1 = (const float*)d_in[17];
  const float* dW2 = (const float*)d_in[18];
  const float* db2 = (const float*)d_in[19];
  const float* dW3 = (const float*)d_in[20];
  const float* db3 = (const float*)d_in[21];
  float* out = (float*)d_out;
  float* ws = (float*)d_ws;

  hipLaunchKernelGGL(k_pre, dim3(658), dim3(256), 0, stream, emb, ae_w, ae_b,
                     ent_w, ent_b, bW, sW1, dW1, ws, out);
  hipLaunchKernelGGL(k_fused, dim3(512, 6), dim3(256), 0, stream, atom_types,
                     positions, bonds, emb, bb, sb1, sW2, sb2, sW3, sb3, db1,
                     dW2, db2, dW3, db3, ws, out);
}